// Round 5
// baseline (454.650 us; speedup 1.0000x reference)
//
#include <hip/hip_runtime.h>
#include <hip/hip_bf16.h>

// Problem constants
#define BB   8
#define NN   4096
#define DD   512
#define HH   8
#define DHH  64
#define WW   128
#define PP   32      // windows = NN / WW
#define DISP 64

typedef __attribute__((ext_vector_type(8))) short bf16x8_t;       // 8 bf16 (4 VGPRs)
typedef __attribute__((ext_vector_type(4))) float f32x4_t;        // MFMA C/D
typedef __attribute__((ext_vector_type(8))) unsigned short u16x8; // raw bf16 bits

__device__ __forceinline__ unsigned short f2bf(float f) {
    unsigned int u = __float_as_uint(f);
    unsigned int r = (u + 0x7FFFu + ((u >> 16) & 1u)) >> 16;  // RNE
    return (unsigned short)r;
}
__device__ __forceinline__ float bf2f(unsigned short u) {
    return __uint_as_float(((unsigned int)u) << 16);
}

__device__ __forceinline__ void gload_lds16(const void* g, void* l) {
    __builtin_amdgcn_global_load_lds(
        (const __attribute__((address_space(1))) unsigned int*)g,
        (__attribute__((address_space(3))) unsigned int*)l, 16, 0, 0);
}

// ---------------------------------------------------------------------------
// Convert x (fp32) -> xb (bf16), applying cyclic shift roll(x,-DISP) so that
// xb rows are in SHIFTED token order (GEMM A reads become linear).
// ---------------------------------------------------------------------------
__global__ __launch_bounds__(256) void cvt_x_shift(const float* __restrict__ x,
                                                   unsigned short* __restrict__ xb) {
    int idx = blockIdx.x * 256 + threadIdx.x;     // 8192*256 threads, 8 elems each
    int e0 = idx * 8;
    int r = e0 >> 9, d = e0 & 511;
    int b = r >> 12, n = r & 4095;
    const float* src = x + (size_t)((b << 12) | ((n + DISP) & 4095)) * 512 + d;
    float4 f0 = *(const float4*)src;
    float4 f1 = *(const float4*)(src + 4);
    u16x8 p;
    p[0] = f2bf(f0.x); p[1] = f2bf(f0.y); p[2] = f2bf(f0.z); p[3] = f2bf(f0.w);
    p[4] = f2bf(f1.x); p[5] = f2bf(f1.y); p[6] = f2bf(f1.z); p[7] = f2bf(f1.w);
    *(u16x8*)(xb + (size_t)r * 512 + d) = p;
}

// ---------------------------------------------------------------------------
// Convert + transpose weights: WqkvT[n][k] (1536x512), WoutT[n][k] (512x512)
// ---------------------------------------------------------------------------
__global__ __launch_bounds__(256) void cvt_w(const float* __restrict__ Wqkv,
                                             const float* __restrict__ Wout,
                                             unsigned short* __restrict__ wqkvT,
                                             unsigned short* __restrict__ woutT) {
    int idx = blockIdx.x * 256 + threadIdx.x;    // 4096*256 = 1,048,576
    if (idx < 786432) {
        int n = idx >> 9, k = idx & 511;
        wqkvT[idx] = f2bf(Wqkv[(size_t)k * 1536 + n]);
    } else {
        int j = idx - 786432;
        int n = j >> 9, k = j & 511;
        woutT[j] = f2bf(Wout[(size_t)k * 512 + n]);
    }
}

// ---------------------------------------------------------------------------
// bf16 MFMA GEMM (m97 structure): 128x128 tile, BK=32, 4 waves, 16x16x32.
// Epilogue scatters q/k/v into PER-WINDOW layouts consumed by win_attn:
//   window base = ((b*8+h)*32+pi)*8192   (16KB block per (b,h,window))
//   q: plain      [w][dh]            -> base + w*64 + dh
//   k: swizzled   [w][dh]            -> base + w*64 + (dh ^ ((w&7)<<3))
//   v: transposed [dh][w], swizzled  -> base + dh*128 + (w ^ ((dh&7)<<3))
// (k/v global layouts ARE the LDS image: win_attn stages them linearly with
//  global_load_lds and reads with the matching XOR on the ds_read address.)
// ---------------------------------------------------------------------------
__global__ __launch_bounds__(256) void gemm_qkv(const unsigned short* __restrict__ A,
                                                const unsigned short* __restrict__ BT,
                                                unsigned short* __restrict__ qw,
                                                unsigned short* __restrict__ kw,
                                                unsigned short* __restrict__ vw) {
    __shared__ unsigned short As[128 * 32];
    __shared__ unsigned short Bs[128 * 32];
    const int tid  = threadIdx.x;
    const int wv   = tid >> 6, lane = tid & 63;
    const int brow = blockIdx.x;            // 256
    const int bcol = blockIdx.y;            // 12
    const int wr = (wv >> 1) * 64, wc = (wv & 1) * 64;
    const int lr = lane >> 4, lc = lane & 15;
    const int kq = lr * 8;

    f32x4_t acc[4][4];
#pragma unroll
    for (int i = 0; i < 4; ++i)
#pragma unroll
        for (int j = 0; j < 4; ++j) acc[i][j] = (f32x4_t)0.f;

    const size_t arow0 = (size_t)brow * 128;
    const size_t brow0 = (size_t)bcol * 128;

    for (int k0 = 0; k0 < 512; k0 += 32) {
#pragma unroll
        for (int i = 0; i < 2; ++i) {
            int chunk = wv * 2 + i;
            int idx = chunk * 64 + lane;        // 0..511
            int row = idx >> 2;                 // 0..127
            int koff = (idx & 3) * 8;
            gload_lds16(A  + (arow0 + row) * 512 + k0 + koff, &As[chunk * 512]);
            gload_lds16(BT + (brow0 + row) * 512 + k0 + koff, &Bs[chunk * 512]);
        }
        __syncthreads();
        bf16x8_t af[4], bfr[4];
#pragma unroll
        for (int mi = 0; mi < 4; ++mi)
            af[mi] = *(const bf16x8_t*)&As[(wr + mi * 16 + lc) * 32 + kq];
#pragma unroll
        for (int nj = 0; nj < 4; ++nj)
            bfr[nj] = *(const bf16x8_t*)&Bs[(wc + nj * 16 + lc) * 32 + kq];
#pragma unroll
        for (int mi = 0; mi < 4; ++mi)
#pragma unroll
            for (int nj = 0; nj < 4; ++nj)
                acc[mi][nj] = __builtin_amdgcn_mfma_f32_16x16x32_bf16(
                    af[mi], bfr[nj], acc[mi][nj], 0, 0, 0);
        __syncthreads();
    }

    // Epilogue: C row = (lane>>4)*4+reg, col = lane&15 within each 16x16 frag
#pragma unroll
    for (int nj = 0; nj < 4; ++nj) {
        int c = bcol * 128 + wc + nj * 16 + lc;
        int which = c >> 9;
        int h  = (c >> 6) & 7;
        int dh = c & 63;
        unsigned short* dst = (which == 0) ? qw : ((which == 1) ? kw : vw);
#pragma unroll
        for (int mi = 0; mi < 4; ++mi)
#pragma unroll
            for (int r = 0; r < 4; ++r) {
                int row = brow * 128 + wr + mi * 16 + lr * 4 + r;
                int b = row >> 12, n = row & 4095;
                int w = n >> 5, pi = n & 31;       // shifted token n = w*32 + pi
                size_t base = ((size_t)((b * 8 + h) * 32 + pi)) * 8192;
                size_t off;
                if (which == 0)      off = base + (size_t)w * 64 + dh;
                else if (which == 1) off = base + (size_t)w * 64 + (dh ^ ((w & 7) << 3));
                else                 off = base + (size_t)dh * 128 + (w ^ ((dh & 7) << 3));
                dst[off] = f2bf(acc[mi][nj][r]);
            }
    }
}

// ---------------------------------------------------------------------------
// out_proj GEMM: out = roll(ao @ Wout + bout, +DISP).
// ---------------------------------------------------------------------------
__global__ __launch_bounds__(256) void gemm_out(const unsigned short* __restrict__ A,
                                                const unsigned short* __restrict__ BT,
                                                const float* __restrict__ bout,
                                                float* __restrict__ out) {
    __shared__ unsigned short As[128 * 32];
    __shared__ unsigned short Bs[128 * 32];
    const int tid  = threadIdx.x;
    const int wv   = tid >> 6, lane = tid & 63;
    const int brow = blockIdx.x;            // 256
    const int bcol = blockIdx.y;            // 4
    const int wr = (wv >> 1) * 64, wc = (wv & 1) * 64;
    const int lr = lane >> 4, lc = lane & 15;
    const int kq = lr * 8;

    f32x4_t acc[4][4];
#pragma unroll
    for (int i = 0; i < 4; ++i)
#pragma unroll
        for (int j = 0; j < 4; ++j) acc[i][j] = (f32x4_t)0.f;

    const size_t arow0 = (size_t)brow * 128;
    const size_t brow0 = (size_t)bcol * 128;

    for (int k0 = 0; k0 < 512; k0 += 32) {
#pragma unroll
        for (int i = 0; i < 2; ++i) {
            int chunk = wv * 2 + i;
            int idx = chunk * 64 + lane;
            int row = idx >> 2;
            int koff = (idx & 3) * 8;
            gload_lds16(A  + (arow0 + row) * 512 + k0 + koff, &As[chunk * 512]);
            gload_lds16(BT + (brow0 + row) * 512 + k0 + koff, &Bs[chunk * 512]);
        }
        __syncthreads();
        bf16x8_t af[4], bfr[4];
#pragma unroll
        for (int mi = 0; mi < 4; ++mi)
            af[mi] = *(const bf16x8_t*)&As[(wr + mi * 16 + lc) * 32 + kq];
#pragma unroll
        for (int nj = 0; nj < 4; ++nj)
            bfr[nj] = *(const bf16x8_t*)&Bs[(wc + nj * 16 + lc) * 32 + kq];
#pragma unroll
        for (int mi = 0; mi < 4; ++mi)
#pragma unroll
            for (int nj = 0; nj < 4; ++nj)
                acc[mi][nj] = __builtin_amdgcn_mfma_f32_16x16x32_bf16(
                    af[mi], bfr[nj], acc[mi][nj], 0, 0, 0);
        __syncthreads();
    }

#pragma unroll
    for (int nj = 0; nj < 4; ++nj) {
        int c = bcol * 128 + wc + nj * 16 + lc;
        float bias = bout[c];
#pragma unroll
        for (int mi = 0; mi < 4; ++mi)
#pragma unroll
            for (int r = 0; r < 4; ++r) {
                int row = brow * 128 + wr + mi * 16 + lr * 4 + r;
                int b = row >> 12, np = row & 4095;
                int dn = (np + DISP) & 4095;                 // roll(+DISP)
                out[(size_t)((b << 12) | dn) * 512 + c] = acc[mi][nj][r] + bias;
            }
    }
}

// ---------------------------------------------------------------------------
// win_attn (MFMA): one block per (b,h,pi) window; 4 waves, wave wv owns
// q-rows [wv*32, wv*32+32).  S kept in accumulators; wave-parallel softmax;
// P through per-wave swizzled LDS; PV via MFMA with transposed V.
// ---------------------------------------------------------------------------
__global__ __launch_bounds__(256) void win_attn(const unsigned short* __restrict__ qw,
                                                const unsigned short* __restrict__ kw,
                                                const unsigned short* __restrict__ vw,
                                                const float* __restrict__ pos,
                                                unsigned short* __restrict__ aob) {
    __shared__ unsigned short K_lds[8192];        // 16KB, [w][dh] swizzled
    __shared__ unsigned short V_lds[8192];        // 16KB, [dh][w] swizzled
    __shared__ unsigned short P_lds[4][4096];     // 8KB per wave, [r][j] swizzled
    __shared__ float pos_lds[255];

    const int tid  = threadIdx.x;
    const int wv   = tid >> 6, lane = tid & 63;
    const int lr   = lane >> 4, lc = lane & 15;
    const int blk  = blockIdx.x;        // b*256 + h*32 + pi
    const int pi   = blk & 31;
    const int h    = (blk >> 5) & 7;
    const int b    = blk >> 8;
    const size_t base = ((size_t)((b * 8 + h) * 32 + pi)) * 8192;
    const unsigned short* qg = qw + base;
    const unsigned short* kg = kw + base;
    const unsigned short* vg = vw + base;

    if (tid < 255) pos_lds[tid] = pos[tid];

    // stage K, V linearly (global layout == LDS image)
#pragma unroll
    for (int i = 0; i < 4; ++i) {
        int c = wv * 4 + i;
        gload_lds16(kg + c * 512 + lane * 8, &K_lds[c * 512]);
        gload_lds16(vg + c * 512 + lane * 8, &V_lds[c * 512]);
    }

    // Q fragments direct from global (plain [w][dh] layout)
    bf16x8_t qf[2][2];
#pragma unroll
    for (int mi = 0; mi < 2; ++mi)
#pragma unroll
        for (int ks = 0; ks < 2; ++ks)
            qf[mi][ks] = *(const bf16x8_t*)(qg + (wv * 32 + mi * 16 + lc) * 64 + ks * 32 + lr * 8);

    __syncthreads();

    // ---- QK^T: S[32][128] per wave in accumulators -------------------------
    f32x4_t sa[2][8];
#pragma unroll
    for (int mi = 0; mi < 2; ++mi)
#pragma unroll
        for (int nj = 0; nj < 8; ++nj) sa[mi][nj] = (f32x4_t)0.f;

#pragma unroll
    for (int ks = 0; ks < 2; ++ks) {
#pragma unroll
        for (int nj = 0; nj < 8; ++nj) {
            int row = nj * 16 + lc;
            int byteoff = ((row * 128) + (ks * 32 + lr * 8) * 2) ^ ((row & 7) << 4);
            bf16x8_t kf = *(const bf16x8_t*)((const char*)K_lds + byteoff);
            sa[0][nj] = __builtin_amdgcn_mfma_f32_16x16x32_bf16(qf[0][ks], kf, sa[0][nj], 0, 0, 0);
            sa[1][nj] = __builtin_amdgcn_mfma_f32_16x16x32_bf16(qf[1][ks], kf, sa[1][nj], 0, 0, 0);
        }
    }

    // ---- bias + mask + wave-parallel softmax; P -> per-wave LDS (bf16) -----
    // lane holds S[i][j]: i = wv*32 + mi*16 + lr*4 + r, j = nj*16 + lc
#pragma unroll
    for (int mi = 0; mi < 2; ++mi)
#pragma unroll
        for (int r = 0; r < 4; ++r) {
            int i = wv * 32 + mi * 16 + lr * 4 + r;
            float mx = -3.0e38f;
#pragma unroll
            for (int nj = 0; nj < 8; ++nj) {
                int j = nj * 16 + lc;
                float s = fmaf(sa[mi][nj][r], 0.125f, pos_lds[j - i + 127]);
                if ((i >= 64) != (j >= 64)) s -= 1e9f;   // shift mask
                sa[mi][nj][r] = s;
                mx = fmaxf(mx, s);
            }
            mx = fmaxf(mx, __shfl_xor(mx, 1));
            mx = fmaxf(mx, __shfl_xor(mx, 2));
            mx = fmaxf(mx, __shfl_xor(mx, 4));
            mx = fmaxf(mx, __shfl_xor(mx, 8));
            float sum = 0.f;
#pragma unroll
            for (int nj = 0; nj < 8; ++nj) {
                float e = __expf(sa[mi][nj][r] - mx);
                sa[mi][nj][r] = e;
                sum += e;
            }
            sum += __shfl_xor(sum, 1);
            sum += __shfl_xor(sum, 2);
            sum += __shfl_xor(sum, 4);
            sum += __shfl_xor(sum, 8);
            float inv = 1.0f / sum;
            int rloc = mi * 16 + lr * 4 + r;
#pragma unroll
            for (int nj = 0; nj < 8; ++nj) {
                int j = nj * 16 + lc;
                int byteoff = ((rloc * 256) + j * 2) ^ ((rloc & 7) << 4);
                *(unsigned short*)((char*)P_lds[wv] + byteoff) = f2bf(sa[mi][nj][r] * inv);
            }
        }
    // (no barrier: P_lds[wv] is same-wave RAW; compiler inserts lgkmcnt)

    // ---- PV: O[32][64] per wave ------------------------------------------
    f32x4_t oa[2][4];
#pragma unroll
    for (int mi = 0; mi < 2; ++mi)
#pragma unroll
        for (int nj = 0; nj < 4; ++nj) oa[mi][nj] = (f32x4_t)0.f;

#pragma unroll
    for (int ks = 0; ks < 4; ++ks) {
        bf16x8_t pa[2], vb[4];
#pragma unroll
        for (int mi = 0; mi < 2; ++mi) {
            int rloc = mi * 16 + lc;
            int byteoff = ((rloc * 256) + (ks * 32 + lr * 8) * 2) ^ ((rloc & 7) << 4);
            pa[mi] = *(const bf16x8_t*)((const char*)P_lds[wv] + byteoff);
        }
#pragma unroll
        for (int nj = 0; nj < 4; ++nj) {
            int dh = nj * 16 + lc;
            int byteoff = ((dh * 256) + (ks * 32 + lr * 8) * 2) ^ ((dh & 7) << 4);
            vb[nj] = *(const bf16x8_t*)((const char*)V_lds + byteoff);
        }
#pragma unroll
        for (int mi = 0; mi < 2; ++mi)
#pragma unroll
            for (int nj = 0; nj < 4; ++nj)
                oa[mi][nj] = __builtin_amdgcn_mfma_f32_16x16x32_bf16(pa[mi], vb[nj], oa[mi][nj], 0, 0, 0);
    }

    // ---- epilogue: O row w -> ao token n' = pi*128 + w ---------------------
    const size_t orow0 = (size_t)b * 4096 + (size_t)pi * 128;
#pragma unroll
    for (int mi = 0; mi < 2; ++mi)
#pragma unroll
        for (int r = 0; r < 4; ++r) {
            int w = wv * 32 + mi * 16 + lr * 4 + r;
            unsigned short* dst = aob + (orow0 + w) * 512 + h * 64;
#pragma unroll
            for (int nj = 0; nj < 4; ++nj)
                dst[nj * 16 + lc] = f2bf(oa[mi][nj][r]);
        }
}

// ---------------------------------------------------------------------------
extern "C" void kernel_launch(void* const* d_in, const int* in_sizes, int n_in,
                              void* d_out, int out_size, void* d_ws, size_t ws_size,
                              hipStream_t stream) {
    (void)in_sizes; (void)n_in; (void)out_size; (void)ws_size;
    const float* x    = (const float*)d_in[0];
    const float* Wqkv = (const float*)d_in[1];
    const float* pos  = (const float*)d_in[2];
    const float* Wout = (const float*)d_in[3];
    const float* bout = (const float*)d_in[4];
    float* out = (float*)d_out;

    const size_t T = (size_t)BB * NN * 512;   // 16,777,216 elems
    unsigned short* xb    = (unsigned short*)d_ws;
    unsigned short* wqkvT = xb + T;           // 786,432
    unsigned short* woutT = wqkvT + 786432;   // 262,144
    unsigned short* qw    = woutT + 262144;
    unsigned short* kw    = qw + T;
    unsigned short* vw    = kw + T;
    unsigned short* aob   = vw + T;

    cvt_x_shift<<<dim3(8192), 256, 0, stream>>>(x, xb);
    cvt_w<<<dim3(4096), 256, 0, stream>>>(Wqkv, Wout, wqkvT, woutT);
    gemm_qkv<<<dim3(256, 12), 256, 0, stream>>>(xb, wqkvT, qw, kw, vw);
    win_attn<<<dim3(2048), 256, 0, stream>>>(qw, kw, vw, pos, aob);
    gemm_out<<<dim3(256, 4), 256, 0, stream>>>(aob, woutT, bout, out);
}

// Round 10
// 307.864 us; speedup vs baseline: 1.4768x; 1.4768x over previous
//
#include <hip/hip_runtime.h>
#include <hip/hip_bf16.h>

// Problem constants
#define BB   8
#define NN   4096
#define DD   512
#define HH   8
#define DHH  64
#define WW   128
#define PP   32      // windows = NN / WW
#define DISP 64

typedef __attribute__((ext_vector_type(8))) short bf16x8_t;       // 8 bf16 (4 VGPRs)
typedef __attribute__((ext_vector_type(4))) float f32x4_t;        // MFMA C/D
typedef __attribute__((ext_vector_type(8))) unsigned short u16x8; // raw bf16 bits

__device__ __forceinline__ unsigned short f2bf(float f) {
    unsigned int u = __float_as_uint(f);
    unsigned int r = (u + 0x7FFFu + ((u >> 16) & 1u)) >> 16;  // RNE
    return (unsigned short)r;
}
__device__ __forceinline__ float bf2f(unsigned short u) {
    return __uint_as_float(((unsigned int)u) << 16);
}

__device__ __forceinline__ void gload_lds16(const void* g, void* l) {
    __builtin_amdgcn_global_load_lds(
        (const __attribute__((address_space(1))) unsigned int*)g,
        (__attribute__((address_space(3))) unsigned int*)l, 16, 0, 0);
}

// ---------------------------------------------------------------------------
// Convert x (fp32) -> xb (bf16), applying cyclic shift roll(x,-DISP) so that
// xb rows are in SHIFTED token order (GEMM A reads become linear).
// ---------------------------------------------------------------------------
__global__ __launch_bounds__(256) void cvt_x_shift(const float* __restrict__ x,
                                                   unsigned short* __restrict__ xb) {
    int idx = blockIdx.x * 256 + threadIdx.x;     // 8192*256 threads, 8 elems each
    int e0 = idx * 8;
    int r = e0 >> 9, d = e0 & 511;
    int b = r >> 12, n = r & 4095;
    const float* src = x + (size_t)((b << 12) | ((n + DISP) & 4095)) * 512 + d;
    float4 f0 = *(const float4*)src;
    float4 f1 = *(const float4*)(src + 4);
    u16x8 p;
    p[0] = f2bf(f0.x); p[1] = f2bf(f0.y); p[2] = f2bf(f0.z); p[3] = f2bf(f0.w);
    p[4] = f2bf(f1.x); p[5] = f2bf(f1.y); p[6] = f2bf(f1.z); p[7] = f2bf(f1.w);
    *(u16x8*)(xb + (size_t)r * 512 + d) = p;
}

// ---------------------------------------------------------------------------
// Convert + transpose weights: WqkvT[n][k] (1536x512), WoutT[n][k] (512x512)
// ---------------------------------------------------------------------------
__global__ __launch_bounds__(256) void cvt_w(const float* __restrict__ Wqkv,
                                             const float* __restrict__ Wout,
                                             unsigned short* __restrict__ wqkvT,
                                             unsigned short* __restrict__ woutT) {
    int idx = blockIdx.x * 256 + threadIdx.x;    // 4096*256 = 1,048,576
    if (idx < 786432) {
        int n = idx >> 9, k = idx & 511;
        wqkvT[idx] = f2bf(Wqkv[(size_t)k * 1536 + n]);
    } else {
        int j = idx - 786432;
        int n = j >> 9, k = j & 511;
        woutT[j] = f2bf(Wout[(size_t)k * 512 + n]);
    }
}

// ---------------------------------------------------------------------------
// bf16 MFMA GEMM for QKV, WINDOW-ALIGNED tiling: brow = b*32 + pi selects one
// window; the tile's 128 M-rows are that window's 128 tokens (global A row
// n = w*32 + pi, stride-32 rows).  This makes the per-window scatter epilogue
// DENSE: each (window,dh) row is written in 8B-contiguous runs that merge
// into full cache lines in L2 (round-5 version amplified writes 4.3x).
//   window base = ((b*8+h)*32+pi)*8192   (16KB block per (b,h,window))
//   q: plain      [w][dh]            -> base + w*64 + dh
//   k: swizzled   [w][dh]            -> base + w*64 + (dh ^ ((w&7)<<3))
//   v: transposed [dh][w], swizzled  -> base + dh*128 + (w ^ ((dh&7)<<3))
// (k/v global layouts ARE the LDS image: win_attn stages them linearly with
//  global_load_lds and reads with the matching XOR on the ds_read address.)
// ---------------------------------------------------------------------------
__global__ __launch_bounds__(256) void gemm_qkv(const unsigned short* __restrict__ A,
                                                const unsigned short* __restrict__ BT,
                                                unsigned short* __restrict__ qw,
                                                unsigned short* __restrict__ kw,
                                                unsigned short* __restrict__ vw) {
    __shared__ unsigned short As[128 * 32];
    __shared__ unsigned short Bs[128 * 32];
    const int tid  = threadIdx.x;
    const int wv   = tid >> 6, lane = tid & 63;
    const int brow = blockIdx.x;            // 256 = b*32 + pi
    const int bcol = blockIdx.y;            // 12
    const int b  = brow >> 5, pi = brow & 31;
    const int wr = (wv >> 1) * 64, wc = (wv & 1) * 64;
    const int lr = lane >> 4, lc = lane & 15;
    const int kq = lr * 8;

    f32x4_t acc[4][4];
#pragma unroll
    for (int i = 0; i < 4; ++i)
#pragma unroll
        for (int j = 0; j < 4; ++j) acc[i][j] = (f32x4_t)0.f;

    // A row for tile-row m (= window token w): b*4096 + m*32 + pi
    const size_t abase = ((size_t)b * 4096 + pi) * 512;
    const size_t brow0 = (size_t)bcol * 128;

    for (int k0 = 0; k0 < 512; k0 += 32) {
#pragma unroll
        for (int i = 0; i < 2; ++i) {
            int chunk = wv * 2 + i;
            int idx = chunk * 64 + lane;        // 0..511
            int row = idx >> 2;                 // 0..127 (= token w)
            int koff = (idx & 3) * 8;
            gload_lds16(A  + abase + (size_t)row * 16384 + k0 + koff, &As[chunk * 512]);
            gload_lds16(BT + (brow0 + row) * 512 + k0 + koff, &Bs[chunk * 512]);
        }
        __syncthreads();
        bf16x8_t af[4], bfr[4];
#pragma unroll
        for (int mi = 0; mi < 4; ++mi)
            af[mi] = *(const bf16x8_t*)&As[(wr + mi * 16 + lc) * 32 + kq];
#pragma unroll
        for (int nj = 0; nj < 4; ++nj)
            bfr[nj] = *(const bf16x8_t*)&Bs[(wc + nj * 16 + lc) * 32 + kq];
#pragma unroll
        for (int mi = 0; mi < 4; ++mi)
#pragma unroll
            for (int nj = 0; nj < 4; ++nj)
                acc[mi][nj] = __builtin_amdgcn_mfma_f32_16x16x32_bf16(
                    af[mi], bfr[nj], acc[mi][nj], 0, 0, 0);
        __syncthreads();
    }

    // Epilogue: C row = (lane>>4)*4+reg (= token w), col = lane&15 in frag
#pragma unroll
    for (int nj = 0; nj < 4; ++nj) {
        int c = bcol * 128 + wc + nj * 16 + lc;
        int which = c >> 9;
        int h  = (c >> 6) & 7;
        int dh = c & 63;
        unsigned short* dst = (which == 0) ? qw : ((which == 1) ? kw : vw);
        size_t base = ((size_t)((b * 8 + h) * 32 + pi)) * 8192;
#pragma unroll
        for (int mi = 0; mi < 4; ++mi)
#pragma unroll
            for (int r = 0; r < 4; ++r) {
                int w = wr + mi * 16 + lr * 4 + r;   // tile row = window token
                size_t off;
                if (which == 0)      off = base + (size_t)w * 64 + dh;
                else if (which == 1) off = base + (size_t)w * 64 + (dh ^ ((w & 7) << 3));
                else                 off = base + (size_t)dh * 128 + (w ^ ((dh & 7) << 3));
                dst[off] = f2bf(acc[mi][nj][r]);
            }
    }
}

// ---------------------------------------------------------------------------
// out_proj GEMM: out = roll(ao @ Wout + bout, +DISP).
// ---------------------------------------------------------------------------
__global__ __launch_bounds__(256) void gemm_out(const unsigned short* __restrict__ A,
                                                const unsigned short* __restrict__ BT,
                                                const float* __restrict__ bout,
                                                float* __restrict__ out) {
    __shared__ unsigned short As[128 * 32];
    __shared__ unsigned short Bs[128 * 32];
    const int tid  = threadIdx.x;
    const int wv   = tid >> 6, lane = tid & 63;
    const int brow = blockIdx.x;            // 256
    const int bcol = blockIdx.y;            // 4
    const int wr = (wv >> 1) * 64, wc = (wv & 1) * 64;
    const int lr = lane >> 4, lc = lane & 15;
    const int kq = lr * 8;

    f32x4_t acc[4][4];
#pragma unroll
    for (int i = 0; i < 4; ++i)
#pragma unroll
        for (int j = 0; j < 4; ++j) acc[i][j] = (f32x4_t)0.f;

    const size_t arow0 = (size_t)brow * 128;
    const size_t brow0 = (size_t)bcol * 128;

    for (int k0 = 0; k0 < 512; k0 += 32) {
#pragma unroll
        for (int i = 0; i < 2; ++i) {
            int chunk = wv * 2 + i;
            int idx = chunk * 64 + lane;
            int row = idx >> 2;
            int koff = (idx & 3) * 8;
            gload_lds16(A  + (arow0 + row) * 512 + k0 + koff, &As[chunk * 512]);
            gload_lds16(BT + (brow0 + row) * 512 + k0 + koff, &Bs[chunk * 512]);
        }
        __syncthreads();
        bf16x8_t af[4], bfr[4];
#pragma unroll
        for (int mi = 0; mi < 4; ++mi)
            af[mi] = *(const bf16x8_t*)&As[(wr + mi * 16 + lc) * 32 + kq];
#pragma unroll
        for (int nj = 0; nj < 4; ++nj)
            bfr[nj] = *(const bf16x8_t*)&Bs[(wc + nj * 16 + lc) * 32 + kq];
#pragma unroll
        for (int mi = 0; mi < 4; ++mi)
#pragma unroll
            for (int nj = 0; nj < 4; ++nj)
                acc[mi][nj] = __builtin_amdgcn_mfma_f32_16x16x32_bf16(
                    af[mi], bfr[nj], acc[mi][nj], 0, 0, 0);
        __syncthreads();
    }

#pragma unroll
    for (int nj = 0; nj < 4; ++nj) {
        int c = bcol * 128 + wc + nj * 16 + lc;
        float bias = bout[c];
#pragma unroll
        for (int mi = 0; mi < 4; ++mi)
#pragma unroll
            for (int r = 0; r < 4; ++r) {
                int row = brow * 128 + wr + mi * 16 + lr * 4 + r;
                int b = row >> 12, np = row & 4095;
                int dn = (np + DISP) & 4095;                 // roll(+DISP)
                out[(size_t)((b << 12) | dn) * 512 + c] = acc[mi][nj][r] + bias;
            }
    }
}

// ---------------------------------------------------------------------------
// win_attn (MFMA): one block per (b,h,pi) window; 4 waves, wave wv owns
// q-rows [wv*32, wv*32+32).  S kept in accumulators; wave-parallel softmax;
// P through per-wave swizzled LDS; PV via MFMA with transposed V.
// ---------------------------------------------------------------------------
__global__ __launch_bounds__(256) void win_attn(const unsigned short* __restrict__ qw,
                                                const unsigned short* __restrict__ kw,
                                                const unsigned short* __restrict__ vw,
                                                const float* __restrict__ pos,
                                                unsigned short* __restrict__ aob) {
    __shared__ unsigned short K_lds[8192];        // 16KB, [w][dh] swizzled
    __shared__ unsigned short V_lds[8192];        // 16KB, [dh][w] swizzled
    __shared__ unsigned short P_lds[4][4096];     // 8KB per wave, [r][j] swizzled
    __shared__ float pos_lds[255];

    const int tid  = threadIdx.x;
    const int wv   = tid >> 6, lane = tid & 63;
    const int lr   = lane >> 4, lc = lane & 15;
    const int blk  = blockIdx.x;        // b*256 + h*32 + pi
    const int pi   = blk & 31;
    const int h    = (blk >> 5) & 7;
    const int b    = blk >> 8;
    const size_t base = ((size_t)((b * 8 + h) * 32 + pi)) * 8192;
    const unsigned short* qg = qw + base;
    const unsigned short* kg = kw + base;
    const unsigned short* vg = vw + base;

    if (tid < 255) pos_lds[tid] = pos[tid];

    // stage K, V linearly (global layout == LDS image)
#pragma unroll
    for (int i = 0; i < 4; ++i) {
        int c = wv * 4 + i;
        gload_lds16(kg + c * 512 + lane * 8, &K_lds[c * 512]);
        gload_lds16(vg + c * 512 + lane * 8, &V_lds[c * 512]);
    }

    // Q fragments direct from global (plain [w][dh] layout)
    bf16x8_t qf[2][2];
#pragma unroll
    for (int mi = 0; mi < 2; ++mi)
#pragma unroll
        for (int ks = 0; ks < 2; ++ks)
            qf[mi][ks] = *(const bf16x8_t*)(qg + (wv * 32 + mi * 16 + lc) * 64 + ks * 32 + lr * 8);

    __syncthreads();

    // ---- QK^T: S[32][128] per wave in accumulators -------------------------
    f32x4_t sa[2][8];
#pragma unroll
    for (int mi = 0; mi < 2; ++mi)
#pragma unroll
        for (int nj = 0; nj < 8; ++nj) sa[mi][nj] = (f32x4_t)0.f;

#pragma unroll
    for (int ks = 0; ks < 2; ++ks) {
#pragma unroll
        for (int nj = 0; nj < 8; ++nj) {
            int row = nj * 16 + lc;
            int byteoff = ((row * 128) + (ks * 32 + lr * 8) * 2) ^ ((row & 7) << 4);
            bf16x8_t kf = *(const bf16x8_t*)((const char*)K_lds + byteoff);
            sa[0][nj] = __builtin_amdgcn_mfma_f32_16x16x32_bf16(qf[0][ks], kf, sa[0][nj], 0, 0, 0);
            sa[1][nj] = __builtin_amdgcn_mfma_f32_16x16x32_bf16(qf[1][ks], kf, sa[1][nj], 0, 0, 0);
        }
    }

    // ---- bias + mask + wave-parallel softmax; P -> per-wave LDS (bf16) -----
    // lane holds S[i][j]: i = wv*32 + mi*16 + lr*4 + r, j = nj*16 + lc
#pragma unroll
    for (int mi = 0; mi < 2; ++mi)
#pragma unroll
        for (int r = 0; r < 4; ++r) {
            int i = wv * 32 + mi * 16 + lr * 4 + r;
            float mx = -3.0e38f;
#pragma unroll
            for (int nj = 0; nj < 8; ++nj) {
                int j = nj * 16 + lc;
                float s = fmaf(sa[mi][nj][r], 0.125f, pos_lds[j - i + 127]);
                if ((i >= 64) != (j >= 64)) s -= 1e9f;   // shift mask
                sa[mi][nj][r] = s;
                mx = fmaxf(mx, s);
            }
            mx = fmaxf(mx, __shfl_xor(mx, 1));
            mx = fmaxf(mx, __shfl_xor(mx, 2));
            mx = fmaxf(mx, __shfl_xor(mx, 4));
            mx = fmaxf(mx, __shfl_xor(mx, 8));
            float sum = 0.f;
#pragma unroll
            for (int nj = 0; nj < 8; ++nj) {
                float e = __expf(sa[mi][nj][r] - mx);
                sa[mi][nj][r] = e;
                sum += e;
            }
            sum += __shfl_xor(sum, 1);
            sum += __shfl_xor(sum, 2);
            sum += __shfl_xor(sum, 4);
            sum += __shfl_xor(sum, 8);
            float inv = 1.0f / sum;
            int rloc = mi * 16 + lr * 4 + r;
#pragma unroll
            for (int nj = 0; nj < 8; ++nj) {
                int j = nj * 16 + lc;
                int byteoff = ((rloc * 256) + j * 2) ^ ((rloc & 7) << 4);
                *(unsigned short*)((char*)P_lds[wv] + byteoff) = f2bf(sa[mi][nj][r] * inv);
            }
        }
    // (no barrier: P_lds[wv] is same-wave RAW; compiler inserts lgkmcnt)

    // ---- PV: O[32][64] per wave ------------------------------------------
    f32x4_t oa[2][4];
#pragma unroll
    for (int mi = 0; mi < 2; ++mi)
#pragma unroll
        for (int nj = 0; nj < 4; ++nj) oa[mi][nj] = (f32x4_t)0.f;

#pragma unroll
    for (int ks = 0; ks < 4; ++ks) {
        bf16x8_t pa[2], vb[4];
#pragma unroll
        for (int mi = 0; mi < 2; ++mi) {
            int rloc = mi * 16 + lc;
            int byteoff = ((rloc * 256) + (ks * 32 + lr * 8) * 2) ^ ((rloc & 7) << 4);
            pa[mi] = *(const bf16x8_t*)((const char*)P_lds[wv] + byteoff);
        }
#pragma unroll
        for (int nj = 0; nj < 4; ++nj) {
            int dh = nj * 16 + lc;
            int byteoff = ((dh * 256) + (ks * 32 + lr * 8) * 2) ^ ((dh & 7) << 4);
            vb[nj] = *(const bf16x8_t*)((const char*)V_lds + byteoff);
        }
#pragma unroll
        for (int mi = 0; mi < 2; ++mi)
#pragma unroll
            for (int nj = 0; nj < 4; ++nj)
                oa[mi][nj] = __builtin_amdgcn_mfma_f32_16x16x32_bf16(pa[mi], vb[nj], oa[mi][nj], 0, 0, 0);
    }

    // ---- epilogue: O row w -> ao token n' = pi*128 + w ---------------------
    const size_t orow0 = (size_t)b * 4096 + (size_t)pi * 128;
#pragma unroll
    for (int mi = 0; mi < 2; ++mi)
#pragma unroll
        for (int r = 0; r < 4; ++r) {
            int w = wv * 32 + mi * 16 + lr * 4 + r;
            unsigned short* dst = aob + (orow0 + w) * 512 + h * 64;
#pragma unroll
            for (int nj = 0; nj < 4; ++nj)
                dst[nj * 16 + lc] = f2bf(oa[mi][nj][r]);
        }
}

// ---------------------------------------------------------------------------
extern "C" void kernel_launch(void* const* d_in, const int* in_sizes, int n_in,
                              void* d_out, int out_size, void* d_ws, size_t ws_size,
                              hipStream_t stream) {
    (void)in_sizes; (void)n_in; (void)out_size; (void)ws_size;
    const float* x    = (const float*)d_in[0];
    const float* Wqkv = (const float*)d_in[1];
    const float* pos  = (const float*)d_in[2];
    const float* Wout = (const float*)d_in[3];
    const float* bout = (const float*)d_in[4];
    float* out = (float*)d_out;

    const size_t T = (size_t)BB * NN * 512;   // 16,777,216 elems
    unsigned short* xb    = (unsigned short*)d_ws;
    unsigned short* wqkvT = xb + T;           // 786,432
    unsigned short* woutT = wqkvT + 786432;   // 262,144
    unsigned short* qw    = woutT + 262144;
    unsigned short* kw    = qw + T;
    unsigned short* vw    = kw + T;
    unsigned short* aob   = vw + T;

    cvt_x_shift<<<dim3(8192), 256, 0, stream>>>(x, xb);
    cvt_w<<<dim3(4096), 256, 0, stream>>>(Wqkv, Wout, wqkvT, woutT);
    gemm_qkv<<<dim3(256, 12), 256, 0, stream>>>(xb, wqkvT, qw, kw, vw);
    win_attn<<<dim3(2048), 256, 0, stream>>>(qw, kw, vw, pos, aob);
    gemm_out<<<dim3(256, 4), 256, 0, stream>>>(aob, woutT, bout, out);
}